// Round 7
// baseline (421.656 us; speedup 1.0000x reference)
//
#include <hip/hip_runtime.h>

#define D_IN 256
#define D_HID 512
#define D_OUT 256
#define LN_EPS 1e-5f
#define SCAN_B 512

typedef __attribute__((ext_vector_type(8))) short bf16x8;
typedef __attribute__((ext_vector_type(4))) float f32x4;

__device__ __forceinline__ ushort f2bf(float x) {
    union { float f; unsigned u; } c; c.f = x;
    unsigned r = c.u + 0x7FFFu + ((c.u >> 16) & 1u);   // round-to-nearest-even
    return (ushort)(r >> 16);
}
__device__ __forceinline__ float bf2f(unsigned b) {
    union { unsigned u; float f; } c; c.u = b << 16;
    return c.f;
}

// ---------------------------------------------------------------------------
// prep: cvt v->bf16 | cvt w1,w2->bf16 | zero cnt     (one launch, grid-split)
// ---------------------------------------------------------------------------
__global__ void prep_kernel(const float* __restrict__ v, const float* __restrict__ w1,
                            const float* __restrict__ w2, ushort* __restrict__ vb,
                            ushort* __restrict__ w1b, ushort* __restrict__ w2b,
                            int* __restrict__ cnt, int n4v, int nzero,
                            int bv, int bw) {
    int b = blockIdx.x, t = threadIdx.x;
    if (b < bv) {
        int i = b * 256 + t;
        if (i < n4v) {
            float4 x = ((const float4*)v)[i];
            ((ushort4*)vb)[i] = make_ushort4(f2bf(x.x), f2bf(x.y), f2bf(x.z), f2bf(x.w));
        }
    } else if (b < bv + bw) {
        int j = (b - bv) * 256 + t;     // 0..65535 float4s (w1: first 32768)
        if (j < 32768) {
            float4 x = ((const float4*)w1)[j];
            ((ushort4*)w1b)[j] = make_ushort4(f2bf(x.x), f2bf(x.y), f2bf(x.z), f2bf(x.w));
        } else {
            int k = j - 32768;
            float4 x = ((const float4*)w2)[k];
            ((ushort4*)w2b)[k] = make_ushort4(f2bf(x.x), f2bf(x.y), f2bf(x.z), f2bf(x.w));
        }
    } else {
        int i = (b - bv - bw) * 256 + t;
        if (i < nzero) cnt[i] = 0;
    }
}

// ---------------------------------------------------------------------------
// CSR build (counting sort by dst)
// ---------------------------------------------------------------------------
__global__ void hist_kernel(const int* __restrict__ dst, int* __restrict__ cnt, int E) {
    int e = blockIdx.x * 256 + threadIdx.x;
    if (e < E) atomicAdd(&cnt[dst[e]], 1);
}

__global__ __launch_bounds__(SCAN_B) void scan1_kernel(const int* __restrict__ cnt,
                                                       int* __restrict__ offs,
                                                       int* __restrict__ bsum, int n) {
    __shared__ int s[SCAN_B];
    int i = blockIdx.x * SCAN_B + threadIdx.x;
    int x = (i < n) ? cnt[i] : 0;
    s[threadIdx.x] = x;
    __syncthreads();
    for (int o = 1; o < SCAN_B; o <<= 1) {
        int t = (threadIdx.x >= (unsigned)o) ? s[threadIdx.x - o] : 0;
        __syncthreads();
        s[threadIdx.x] += t;
        __syncthreads();
    }
    if (i < n) offs[i] = s[threadIdx.x] - x;
    if (threadIdx.x == SCAN_B - 1) bsum[blockIdx.x] = s[threadIdx.x];
}

// offs[i] += sum(bsum[0..blk-1]); cursor=offs; offs[n]=E   (scan2 folded in)
__global__ __launch_bounds__(SCAN_B) void scan3_kernel(int* __restrict__ offs,
                                                       int* __restrict__ cursor,
                                                       const int* __restrict__ bsum,
                                                       int n, int E, int nb) {
    __shared__ int s[SCAN_B];
    int t = threadIdx.x;
    s[t] = (t < nb && t < (int)blockIdx.x) ? bsum[t] : 0;
    __syncthreads();
    for (int o = SCAN_B / 2; o > 0; o >>= 1) {
        if (t < o) s[t] += s[t + o];
        __syncthreads();
    }
    int base = s[0];
    int i = blockIdx.x * SCAN_B + t;
    if (i < n) {
        int v0 = offs[i] + base;
        offs[i] = v0;
        cursor[i] = v0;
    }
    if (i == 0) offs[n] = E;
}

// counting-sort fill: one 8B scatter per edge (src, weight-bits)
__global__ void fill_kernel(const int* __restrict__ src, const int* __restrict__ dst,
                            const float* __restrict__ ew, int* __restrict__ cursor,
                            int2* __restrict__ perm, int E) {
    int e = blockIdx.x * 256 + threadIdx.x;
    if (e >= E) return;
    int p = atomicAdd(&cursor[dst[e]], 1);
    perm[p] = make_int2(src[e], __float_as_int(ew[e]));
}

// ---------------------------------------------------------------------------
// MEGA: per 32-node block, fully fused
//   phase1: gather agg tile (bf16) -> LDS As            [stride 264]
//   phase2: GEMM1 (Kx256->512) w1 staged 32k-chunks     [Bs1 stride 32]
//   epi1:   bias+LN+ReLU -> LDS Hs (bf16)               [stride 520, aliases As+Bs1]
//   phase3: GEMM2 (Kx512->256) w2 staged 32k-chunks     [Bs2 stride 32]
//   epi2:   bias+LN+ReLU -> out (fp32, global)
// LDS: lds[24832] ushorts = 49.6 KB; As@0 (8448), Bs1@8448 (16384),
//      Hs@0 (16640), Bs2@16640 (8192).
// ---------------------------------------------------------------------------
#define ASTR 264
#define HSTR 520
#define BS1_OFF 8448
#define BS2_OFF 16640

__global__ __launch_bounds__(256) void mega_kernel(
    const ushort* __restrict__ vb, const float* __restrict__ eps_p,
    const int* __restrict__ offs, const int2* __restrict__ perm,
    const ushort* __restrict__ w1b, const ushort* __restrict__ w2b,
    const float* __restrict__ b1, const float* __restrict__ g1, const float* __restrict__ be1,
    const float* __restrict__ b2, const float* __restrict__ g2, const float* __restrict__ be2,
    float* __restrict__ out, int N) {
    __shared__ ushort lds[24832];
    __shared__ float red[2][32][4];
    __shared__ float mu_s[32], rs_s[32];

    int t = threadIdx.x;
    int w = t >> 6, lane = t & 63;
    int row0 = blockIdx.x * 32;
    int fr = lane & 15, q = lane >> 4, kb = q * 8;
    int lrow = lane >> 2, lcol = (lane & 3) * 8;

    // ---------------- phase 1: gather (8 nodes per wave) ----------------
    float epsv = eps_p[0];
    for (int s = 0; s < 8; ++s) {
        int lnode = w * 8 + s;
        int node = row0 + lnode;
        float a0 = 0.f, a1 = 0.f, a2 = 0.f, a3 = 0.f;
        if (node < N) {
            int beg = offs[node], end = offs[node + 1];
            int i = beg;
            for (; i + 4 <= end; i += 4) {
                int2 p0 = perm[i + 0], p1 = perm[i + 1], p2 = perm[i + 2], p3 = perm[i + 3];
                float w0 = __int_as_float(p0.y), w1f = __int_as_float(p1.y);
                float w2f = __int_as_float(p2.y), w3 = __int_as_float(p3.y);
                ushort4 r0 = ((const ushort4*)(vb + (size_t)p0.x * D_IN))[lane];
                ushort4 r1 = ((const ushort4*)(vb + (size_t)p1.x * D_IN))[lane];
                ushort4 r2 = ((const ushort4*)(vb + (size_t)p2.x * D_IN))[lane];
                ushort4 r3 = ((const ushort4*)(vb + (size_t)p3.x * D_IN))[lane];
                a0 += w0 * bf2f(r0.x) + w1f * bf2f(r1.x) + w2f * bf2f(r2.x) + w3 * bf2f(r3.x);
                a1 += w0 * bf2f(r0.y) + w1f * bf2f(r1.y) + w2f * bf2f(r2.y) + w3 * bf2f(r3.y);
                a2 += w0 * bf2f(r0.z) + w1f * bf2f(r1.z) + w2f * bf2f(r2.z) + w3 * bf2f(r3.z);
                a3 += w0 * bf2f(r0.w) + w1f * bf2f(r1.w) + w2f * bf2f(r2.w) + w3 * bf2f(r3.w);
            }
            for (; i < end; ++i) {
                int2 p = perm[i];
                float wf = __int_as_float(p.y);
                ushort4 r = ((const ushort4*)(vb + (size_t)p.x * D_IN))[lane];
                a0 += wf * bf2f(r.x); a1 += wf * bf2f(r.y);
                a2 += wf * bf2f(r.z); a3 += wf * bf2f(r.w);
            }
            ushort4 m = ((const ushort4*)(vb + (size_t)node * D_IN))[lane];
            a0 += epsv * bf2f(m.x); a1 += epsv * bf2f(m.y);
            a2 += epsv * bf2f(m.z); a3 += epsv * bf2f(m.w);
        }
        uint2 pk;
        pk.x = (unsigned)f2bf(a0) | ((unsigned)f2bf(a1) << 16);
        pk.y = (unsigned)f2bf(a2) | ((unsigned)f2bf(a3) << 16);
        *(uint2*)&lds[lnode * ASTR + lane * 4] = pk;
    }
    __syncthreads();

    // ---------------- phase 2: GEMM1 (K=256 -> 512 cols) ----------------
    f32x4 acc[2][8];
    #pragma unroll
    for (int i = 0; i < 2; ++i)
        #pragma unroll
        for (int c = 0; c < 8; ++c) {
            f32x4 z = {0.f, 0.f, 0.f, 0.f};
            acc[i][c] = z;
        }

    for (int k0 = 0; k0 < D_IN; k0 += 32) {
        #pragma unroll
        for (int c = 0; c < 8; ++c) {
            int br = w * 128 + c * 16 + lrow;
            const ushort* gp = w1b + (size_t)br * D_IN + k0 + lcol;
            __builtin_amdgcn_global_load_lds(
                (const __attribute__((address_space(1))) void*)gp,
                (__attribute__((address_space(3))) void*)(&lds[BS1_OFF + (w * 128 + c * 16) * 32]),
                16, 0, 0);
        }
        __syncthreads();
        bf16x8 af[2], bf[8];
        af[0] = *(const bf16x8*)&lds[fr * ASTR + k0 + kb];
        af[1] = *(const bf16x8*)&lds[(16 + fr) * ASTR + k0 + kb];
        #pragma unroll
        for (int c = 0; c < 8; ++c)
            bf[c] = *(const bf16x8*)&lds[BS1_OFF + (w * 128 + c * 16 + fr) * 32 + kb];
        #pragma unroll
        for (int i = 0; i < 2; ++i)
            #pragma unroll
            for (int c = 0; c < 8; ++c)
                acc[i][c] = __builtin_amdgcn_mfma_f32_16x16x32_bf16(af[i], bf[c], acc[i][c], 0, 0, 0);
        __syncthreads();
    }

    // ---------------- epilogue 1: bias + LN + ReLU -> Hs ----------------
    {
        float bi[8], gg[8], bb[8];
        #pragma unroll
        for (int c = 0; c < 8; ++c) {
            int col = w * 128 + c * 16 + fr;
            bi[c] = b1[col]; gg[c] = g1[col]; bb[c] = be1[col];
        }
        #pragma unroll
        for (int i = 0; i < 2; ++i) {
            #pragma unroll
            for (int r = 0; r < 4; ++r) {
                float s = 0.f, sq = 0.f;
                #pragma unroll
                for (int c = 0; c < 8; ++c) {
                    float x = acc[i][c][r] + bi[c];
                    acc[i][c][r] = x;
                    s += x; sq += x * x;
                }
                #pragma unroll
                for (int o = 1; o < 16; o <<= 1) {
                    s  += __shfl_xor(s, o, 64);
                    sq += __shfl_xor(sq, o, 64);
                }
                if (fr == 0) {
                    int row = i * 16 + q * 4 + r;
                    red[0][row][w] = s;
                    red[1][row][w] = sq;
                }
            }
        }
        __syncthreads();
        if (t < 32) {
            float s  = red[0][t][0] + red[0][t][1] + red[0][t][2] + red[0][t][3];
            float sq = red[1][t][0] + red[1][t][1] + red[1][t][2] + red[1][t][3];
            float mu = s / (float)D_HID;
            float var = sq / (float)D_HID - mu * mu;
            mu_s[t] = mu;
            rs_s[t] = rsqrtf(var + LN_EPS);
        }
        __syncthreads();
        // write Hs (aliases As/Bs1 — all reads completed before the syncs above)
        #pragma unroll
        for (int i = 0; i < 2; ++i) {
            #pragma unroll
            for (int r = 0; r < 4; ++r) {
                int row = i * 16 + q * 4 + r;
                float mu = mu_s[row], rs = rs_s[row];
                #pragma unroll
                for (int c = 0; c < 8; ++c) {
                    int col = w * 128 + c * 16 + fr;
                    float y = (acc[i][c][r] - mu) * rs * gg[c] + bb[c];
                    lds[row * HSTR + col] = f2bf(fmaxf(y, 0.f));
                }
            }
        }
    }
    __syncthreads();

    // ---------------- phase 3: GEMM2 (K=512 -> 256 cols) ----------------
    f32x4 acc2[2][4];
    #pragma unroll
    for (int i = 0; i < 2; ++i)
        #pragma unroll
        for (int c = 0; c < 4; ++c) {
            f32x4 z = {0.f, 0.f, 0.f, 0.f};
            acc2[i][c] = z;
        }

    for (int k0 = 0; k0 < D_HID; k0 += 32) {
        #pragma unroll
        for (int c = 0; c < 4; ++c) {
            int br = w * 64 + c * 16 + lrow;
            const ushort* gp = w2b + (size_t)br * D_HID + k0 + lcol;
            __builtin_amdgcn_global_load_lds(
                (const __attribute__((address_space(1))) void*)gp,
                (__attribute__((address_space(3))) void*)(&lds[BS2_OFF + (w * 64 + c * 16) * 32]),
                16, 0, 0);
        }
        __syncthreads();
        bf16x8 af[2], bf[4];
        af[0] = *(const bf16x8*)&lds[fr * HSTR + k0 + kb];
        af[1] = *(const bf16x8*)&lds[(16 + fr) * HSTR + k0 + kb];
        #pragma unroll
        for (int c = 0; c < 4; ++c)
            bf[c] = *(const bf16x8*)&lds[BS2_OFF + (w * 64 + c * 16 + fr) * 32 + kb];
        #pragma unroll
        for (int i = 0; i < 2; ++i)
            #pragma unroll
            for (int c = 0; c < 4; ++c)
                acc2[i][c] = __builtin_amdgcn_mfma_f32_16x16x32_bf16(af[i], bf[c], acc2[i][c], 0, 0, 0);
        __syncthreads();
    }

    // ---------------- epilogue 2: bias + LN + ReLU -> out ----------------
    {
        float bi[4], gg[4], bb[4];
        #pragma unroll
        for (int c = 0; c < 4; ++c) {
            int col = w * 64 + c * 16 + fr;
            bi[c] = b2[col]; gg[c] = g2[col]; bb[c] = be2[col];
        }
        #pragma unroll
        for (int i = 0; i < 2; ++i) {
            #pragma unroll
            for (int r = 0; r < 4; ++r) {
                float s = 0.f, sq = 0.f;
                #pragma unroll
                for (int c = 0; c < 4; ++c) {
                    float x = acc2[i][c][r] + bi[c];
                    acc2[i][c][r] = x;
                    s += x; sq += x * x;
                }
                #pragma unroll
                for (int o = 1; o < 16; o <<= 1) {
                    s  += __shfl_xor(s, o, 64);
                    sq += __shfl_xor(sq, o, 64);
                }
                if (fr == 0) {
                    int row = i * 16 + q * 4 + r;
                    red[0][row][w] = s;
                    red[1][row][w] = sq;
                }
            }
        }
        __syncthreads();
        if (t < 32) {
            float s  = red[0][t][0] + red[0][t][1] + red[0][t][2] + red[0][t][3];
            float sq = red[1][t][0] + red[1][t][1] + red[1][t][2] + red[1][t][3];
            float mu = s / (float)D_OUT;
            float var = sq / (float)D_OUT - mu * mu;
            mu_s[t] = mu;
            rs_s[t] = rsqrtf(var + LN_EPS);
        }
        __syncthreads();
        #pragma unroll
        for (int i = 0; i < 2; ++i) {
            #pragma unroll
            for (int r = 0; r < 4; ++r) {
                int row = i * 16 + q * 4 + r;
                int grow = row0 + row;
                if (grow >= N) continue;
                float mu = mu_s[row], rs = rs_s[row];
                #pragma unroll
                for (int c = 0; c < 4; ++c) {
                    int col = w * 64 + c * 16 + fr;
                    float y = (acc2[i][c][r] - mu) * rs * gg[c] + bb[c];
                    out[(size_t)grow * D_OUT + col] = fmaxf(y, 0.f);
                }
            }
        }
    }
}

// ---------------------------------------------------------------------------
extern "C" void kernel_launch(void* const* d_in, const int* in_sizes, int n_in,
                              void* d_out, int out_size, void* d_ws, size_t ws_size,
                              hipStream_t stream) {
    const float* v     = (const float*)d_in[0];
    const float* ew    = (const float*)d_in[1];
    const float* eps   = (const float*)d_in[2];
    const float* w1    = (const float*)d_in[3];
    const float* b1    = (const float*)d_in[4];
    const float* g1    = (const float*)d_in[5];
    const float* beta1 = (const float*)d_in[6];
    const float* w2    = (const float*)d_in[7];
    const float* b2    = (const float*)d_in[8];
    const float* g2    = (const float*)d_in[9];
    const float* beta2 = (const float*)d_in[10];
    const int*   src   = (const int*)d_in[11];
    const int*   dst   = (const int*)d_in[12];

    int N = in_sizes[0] / D_IN;     // 50000
    int E = in_sizes[1];            // 800000

    float* out = (float*)d_out;

    // workspace layout (256B-aligned chunks)
    char* ws = (char*)d_ws;
    size_t off = 0;
    ushort* vb   = (ushort*)(ws + off); off += (size_t)N * D_IN * 2;            // 25.6 MB
    ushort* w1b  = (ushort*)(ws + off); off += (size_t)D_HID * D_IN * 2;        // 256 KB
    ushort* w2b  = (ushort*)(ws + off); off += (size_t)D_OUT * D_HID * 2;       // 256 KB
    int* offs     = (int*)(ws + off); off += (size_t)(N + 256) * 4;
    int* cursor   = (int*)(ws + off); off += (size_t)(N + 256) * 4;
    int* bsum     = (int*)(ws + off); off += 1024;
    int2* perm    = (int2*)(ws + off); off += (size_t)E * 8;                    // 6.4 MB

    int nb = (N + SCAN_B - 1) / SCAN_B;
    int n4v = N * (D_IN / 4);
    int bv = (n4v + 255) / 256;
    int bw = 256;                     // 65536 float4s of weights
    int bz = (N + 255) / 256;

    // 1) prep: casts + zero (cursor doubles as cnt)
    prep_kernel<<<bv + bw + bz, 256, 0, stream>>>(v, w1, w2, vb, w1b, w2b,
                                                  cursor, n4v, N, bv, bw);

    // 2) CSR by dst
    hist_kernel<<<(E + 255) / 256, 256, 0, stream>>>(dst, cursor, E);
    scan1_kernel<<<nb, SCAN_B, 0, stream>>>(cursor, offs, bsum, N);
    scan3_kernel<<<nb, SCAN_B, 0, stream>>>(offs, cursor, bsum, N, E, nb);
    fill_kernel<<<(E + 255) / 256, 256, 0, stream>>>(src, dst, ew, cursor, perm, E);

    // 3) mega: gather + GEMM1 + LN1 + GEMM2 + LN2
    int mblocks = (N + 31) / 32;
    mega_kernel<<<mblocks, 256, 0, stream>>>(vb, eps, offs, perm, w1b, w2b,
                                             b1, g1, beta1, b2, g2, beta2, out, N);
}

// Round 8
// 353.784 us; speedup vs baseline: 1.1918x; 1.1918x over previous
//
#include <hip/hip_runtime.h>

#define D_IN 256
#define D_HID 512
#define D_OUT 256
#define LN_EPS 1e-5f
#define SCAN_B 512

typedef __attribute__((ext_vector_type(8))) short bf16x8;
typedef __attribute__((ext_vector_type(4))) float f32x4;

__device__ __forceinline__ ushort f2bf(float x) {
    union { float f; unsigned u; } c; c.f = x;
    unsigned r = c.u + 0x7FFFu + ((c.u >> 16) & 1u);   // round-to-nearest-even
    return (ushort)(r >> 16);
}
__device__ __forceinline__ float bf2f(unsigned b) {
    union { unsigned u; float f; } c; c.u = b << 16;
    return c.f;
}

// ---------------------------------------------------------------------------
// prep: cvt v->bf16 | cvt w1,w2->bf16 | zero cnt     (one launch, grid-split)
// ---------------------------------------------------------------------------
__global__ void prep_kernel(const float* __restrict__ v, const float* __restrict__ w1,
                            const float* __restrict__ w2, ushort* __restrict__ vb,
                            ushort* __restrict__ w1b, ushort* __restrict__ w2b,
                            int* __restrict__ cnt, int n4v, int nzero,
                            int bv, int bw) {
    int b = blockIdx.x, t = threadIdx.x;
    if (b < bv) {
        int i = b * 256 + t;
        if (i < n4v) {
            float4 x = ((const float4*)v)[i];
            ((ushort4*)vb)[i] = make_ushort4(f2bf(x.x), f2bf(x.y), f2bf(x.z), f2bf(x.w));
        }
    } else if (b < bv + bw) {
        int j = (b - bv) * 256 + t;     // 0..65535 float4s (w1: first 32768)
        if (j < 32768) {
            float4 x = ((const float4*)w1)[j];
            ((ushort4*)w1b)[j] = make_ushort4(f2bf(x.x), f2bf(x.y), f2bf(x.z), f2bf(x.w));
        } else {
            int k = j - 32768;
            float4 x = ((const float4*)w2)[k];
            ((ushort4*)w2b)[k] = make_ushort4(f2bf(x.x), f2bf(x.y), f2bf(x.z), f2bf(x.w));
        }
    } else {
        int i = (b - bv - bw) * 256 + t;
        if (i < nzero) cnt[i] = 0;
    }
}

// ---------------------------------------------------------------------------
// CSR build (counting sort by dst)
// ---------------------------------------------------------------------------
__global__ void hist_kernel(const int* __restrict__ dst, int* __restrict__ cnt, int E) {
    int e = blockIdx.x * 256 + threadIdx.x;
    if (e < E) atomicAdd(&cnt[dst[e]], 1);
}

__global__ __launch_bounds__(SCAN_B) void scan1_kernel(const int* __restrict__ cnt,
                                                       int* __restrict__ offs,
                                                       int* __restrict__ bsum, int n) {
    __shared__ int s[SCAN_B];
    int i = blockIdx.x * SCAN_B + threadIdx.x;
    int x = (i < n) ? cnt[i] : 0;
    s[threadIdx.x] = x;
    __syncthreads();
    for (int o = 1; o < SCAN_B; o <<= 1) {
        int t = (threadIdx.x >= (unsigned)o) ? s[threadIdx.x - o] : 0;
        __syncthreads();
        s[threadIdx.x] += t;
        __syncthreads();
    }
    if (i < n) offs[i] = s[threadIdx.x] - x;
    if (threadIdx.x == SCAN_B - 1) bsum[blockIdx.x] = s[threadIdx.x];
}

// offs[i] += sum(bsum[0..blk-1]); cursor=offs; offs[n]=E   (scan2 folded in)
__global__ __launch_bounds__(SCAN_B) void scan3_kernel(int* __restrict__ offs,
                                                       int* __restrict__ cursor,
                                                       const int* __restrict__ bsum,
                                                       int n, int E, int nb) {
    __shared__ int s[SCAN_B];
    int t = threadIdx.x;
    s[t] = (t < nb && t < (int)blockIdx.x) ? bsum[t] : 0;
    __syncthreads();
    for (int o = SCAN_B / 2; o > 0; o >>= 1) {
        if (t < o) s[t] += s[t + o];
        __syncthreads();
    }
    int base = s[0];
    int i = blockIdx.x * SCAN_B + t;
    if (i < n) {
        int v0 = offs[i] + base;
        offs[i] = v0;
        cursor[i] = v0;
    }
    if (i == 0) offs[n] = E;
}

// counting-sort fill: one 8B scatter per edge (src, weight-bits)
__global__ void fill_kernel(const int* __restrict__ src, const int* __restrict__ dst,
                            const float* __restrict__ ew, int* __restrict__ cursor,
                            int2* __restrict__ perm, int E) {
    int e = blockIdx.x * 256 + threadIdx.x;
    if (e >= E) return;
    int p = atomicAdd(&cursor[dst[e]], 1);
    perm[p] = make_int2(src[e], __float_as_int(ew[e]));
}

// ---------------------------------------------------------------------------
// agg_bf16[n] = bf16( eps*vb[n] + sum_{e:dst=n} w_e * vb[src_e] )
// one wave/node, bf16 gather, int2 edge records, unroll x4
// ---------------------------------------------------------------------------
__global__ __launch_bounds__(256) void aggregate_kernel(
    const ushort* __restrict__ vb, const float* __restrict__ eps_p,
    const int* __restrict__ offs, const int2* __restrict__ perm,
    ushort* __restrict__ aggb, int N) {
    int node = blockIdx.x * 4 + (threadIdx.x >> 6);
    if (node >= N) return;
    int lane = threadIdx.x & 63;
    int beg = offs[node], end = offs[node + 1];
    float a0 = 0.f, a1 = 0.f, a2 = 0.f, a3 = 0.f;

    int i = beg;
    for (; i + 4 <= end; i += 4) {
        int2 p0 = perm[i + 0], p1 = perm[i + 1], p2 = perm[i + 2], p3 = perm[i + 3];
        float w0 = __int_as_float(p0.y), w1 = __int_as_float(p1.y);
        float w2 = __int_as_float(p2.y), w3 = __int_as_float(p3.y);
        ushort4 r0 = ((const ushort4*)(vb + (size_t)p0.x * D_IN))[lane];
        ushort4 r1 = ((const ushort4*)(vb + (size_t)p1.x * D_IN))[lane];
        ushort4 r2 = ((const ushort4*)(vb + (size_t)p2.x * D_IN))[lane];
        ushort4 r3 = ((const ushort4*)(vb + (size_t)p3.x * D_IN))[lane];
        a0 += w0 * bf2f(r0.x) + w1 * bf2f(r1.x) + w2 * bf2f(r2.x) + w3 * bf2f(r3.x);
        a1 += w0 * bf2f(r0.y) + w1 * bf2f(r1.y) + w2 * bf2f(r2.y) + w3 * bf2f(r3.y);
        a2 += w0 * bf2f(r0.z) + w1 * bf2f(r1.z) + w2 * bf2f(r2.z) + w3 * bf2f(r3.z);
        a3 += w0 * bf2f(r0.w) + w1 * bf2f(r1.w) + w2 * bf2f(r2.w) + w3 * bf2f(r3.w);
    }
    for (; i < end; ++i) {
        int2 p = perm[i];
        float w = __int_as_float(p.y);
        ushort4 r = ((const ushort4*)(vb + (size_t)p.x * D_IN))[lane];
        a0 += w * bf2f(r.x); a1 += w * bf2f(r.y);
        a2 += w * bf2f(r.z); a3 += w * bf2f(r.w);
    }
    float eps = eps_p[0];
    ushort4 m = ((const ushort4*)(vb + (size_t)node * D_IN))[lane];
    a0 += eps * bf2f(m.x); a1 += eps * bf2f(m.y);
    a2 += eps * bf2f(m.z); a3 += eps * bf2f(m.w);
    ((ushort4*)(aggb + (size_t)node * D_IN))[lane] =
        make_ushort4(f2bf(a0), f2bf(a1), f2bf(a2), f2bf(a3));
}

// ---------------------------------------------------------------------------
// Fused GEMM + bias + LayerNorm + ReLU.
//   out[m][:] = relu(LN(A[m][:] @ B^T + bias) * g + beta)
// Block = 64 rows x COLS (full width), 512 threads / 8 waves; wave w owns
// cols [w*CW,(w+1)*CW). 16x16x32 bf16 MFMA, BK=32, global_load_lds staging.
// COLS in {256,512}; K mult of 32; M guarded.
// ---------------------------------------------------------------------------
template <int COLS, int WRITE_BF16>
__global__ __launch_bounds__(512) void gemm_ln_kernel(
    const ushort* __restrict__ A, const ushort* __restrict__ B,
    const float* __restrict__ bias, const float* __restrict__ g,
    const float* __restrict__ beta, void* __restrict__ Cv, int M, int K) {
    constexpr int CW = COLS / 8;      // cols per wave (64 | 32)
    constexpr int CF = CW / 16;       // col fragments per wave (4 | 2)
    __shared__ ushort As[64 * 32];
    __shared__ ushort Bs[COLS * 32];
    __shared__ float red[2][64][8];   // [sum|sq][row][wave]
    __shared__ float mu_s[64], rs_s[64];

    int t = threadIdx.x;
    int w = t >> 6, lane = t & 63;
    int row0 = blockIdx.x * 64;
    int fr = lane & 15, q = lane >> 4, kb = q * 8;
    int lrow = lane >> 2;             // 0..15: row within 16-row staging chunk
    int lcol = (lane & 3) * 8;        // k-offset (8 bf16 = 16B)

    f32x4 acc[4][CF];
    #pragma unroll
    for (int i = 0; i < 4; ++i)
        #pragma unroll
        for (int c = 0; c < CF; ++c) {
            f32x4 z = {0.f, 0.f, 0.f, 0.f};
            acc[i][c] = z;
        }

    for (int k0 = 0; k0 < K; k0 += 32) {
        // stage B: wave w stages its CW cols in 16-row chunks
        #pragma unroll
        for (int c = 0; c < CF; ++c) {
            int br = w * CW + c * 16 + lrow;
            const ushort* gp = B + (size_t)br * K + k0 + lcol;
            __builtin_amdgcn_global_load_lds(
                (const __attribute__((address_space(1))) void*)gp,
                (__attribute__((address_space(3))) void*)(&Bs[(w * CW + c * 16) * 32]),
                16, 0, 0);
        }
        // stage A: waves 0..3 stage 16 rows each
        if (w < 4) {
            int ar = row0 + w * 16 + lrow;
            if (ar > M - 1) ar = M - 1;
            const ushort* gp = A + (size_t)ar * K + k0 + lcol;
            __builtin_amdgcn_global_load_lds(
                (const __attribute__((address_space(1))) void*)gp,
                (__attribute__((address_space(3))) void*)(&As[(w * 16) * 32]),
                16, 0, 0);
        }
        __syncthreads();

        bf16x8 af[4], bf[CF];
        #pragma unroll
        for (int i = 0; i < 4; ++i)
            af[i] = *(const bf16x8*)&As[(i * 16 + fr) * 32 + kb];
        #pragma unroll
        for (int c = 0; c < CF; ++c)
            bf[c] = *(const bf16x8*)&Bs[(w * CW + c * 16 + fr) * 32 + kb];
        #pragma unroll
        for (int i = 0; i < 4; ++i)
            #pragma unroll
            for (int c = 0; c < CF; ++c)
                acc[i][c] = __builtin_amdgcn_mfma_f32_16x16x32_bf16(af[i], bf[c], acc[i][c], 0, 0, 0);
        __syncthreads();
    }

    // epilogue: bias, then per-row LN stats
    float bi[CF], gg[CF], bb[CF];
    #pragma unroll
    for (int c = 0; c < CF; ++c) {
        int col = w * CW + c * 16 + fr;
        bi[c] = bias[col]; gg[c] = g[col]; bb[c] = beta[col];
    }

    // per-(i,r): sum over this wave's CW cols via 16-lane butterfly over fr
    #pragma unroll
    for (int i = 0; i < 4; ++i) {
        #pragma unroll
        for (int r = 0; r < 4; ++r) {
            float s = 0.f, sq = 0.f;
            #pragma unroll
            for (int c = 0; c < CF; ++c) {
                float x = acc[i][c][r] + bi[c];
                acc[i][c][r] = x;
                s += x; sq += x * x;
            }
            #pragma unroll
            for (int o = 1; o < 16; o <<= 1) {
                s  += __shfl_xor(s, o, 64);
                sq += __shfl_xor(sq, o, 64);
            }
            if (fr == 0) {
                int row = i * 16 + q * 4 + r;
                red[0][row][w] = s;
                red[1][row][w] = sq;
            }
        }
    }
    __syncthreads();
    if (t < 64) {
        float s = 0.f, sq = 0.f;
        #pragma unroll
        for (int j = 0; j < 8; ++j) { s += red[0][t][j]; sq += red[1][t][j]; }
        float mu = s / (float)COLS;
        float var = sq / (float)COLS - mu * mu;
        mu_s[t] = mu;
        rs_s[t] = rsqrtf(var + LN_EPS);
    }
    __syncthreads();

    #pragma unroll
    for (int i = 0; i < 4; ++i) {
        #pragma unroll
        for (int r = 0; r < 4; ++r) {
            int row = i * 16 + q * 4 + r;
            int grow = row0 + row;
            if (grow >= M) continue;
            float mu = mu_s[row], rs = rs_s[row];
            #pragma unroll
            for (int c = 0; c < CF; ++c) {
                int col = w * CW + c * 16 + fr;
                float y = (acc[i][c][r] - mu) * rs * gg[c] + bb[c];
                y = fmaxf(y, 0.f);
                if (WRITE_BF16)
                    ((ushort*)Cv)[(size_t)grow * COLS + col] = f2bf(y);
                else
                    ((float*)Cv)[(size_t)grow * COLS + col] = y;
            }
        }
    }
}

// ---------------------------------------------------------------------------
extern "C" void kernel_launch(void* const* d_in, const int* in_sizes, int n_in,
                              void* d_out, int out_size, void* d_ws, size_t ws_size,
                              hipStream_t stream) {
    const float* v     = (const float*)d_in[0];
    const float* ew    = (const float*)d_in[1];
    const float* eps   = (const float*)d_in[2];
    const float* w1    = (const float*)d_in[3];
    const float* b1    = (const float*)d_in[4];
    const float* g1    = (const float*)d_in[5];
    const float* beta1 = (const float*)d_in[6];
    const float* w2    = (const float*)d_in[7];
    const float* b2    = (const float*)d_in[8];
    const float* g2    = (const float*)d_in[9];
    const float* beta2 = (const float*)d_in[10];
    const int*   src   = (const int*)d_in[11];
    const int*   dst   = (const int*)d_in[12];

    int N = in_sizes[0] / D_IN;     // 50000
    int E = in_sizes[1];            // 800000

    float* out = (float*)d_out;

    // workspace layout (256B-aligned chunks)
    char* ws = (char*)d_ws;
    size_t off = 0;
    ushort* vb   = (ushort*)(ws + off); off += (size_t)N * D_IN * 2;            // 25.6 MB
    ushort* aggb = (ushort*)(ws + off); off += (size_t)N * D_IN * 2;            // 25.6 MB
    ushort* h1b  = (ushort*)(ws + off); off += (size_t)N * D_HID * 2;           // 51.2 MB
    ushort* w1b  = (ushort*)(ws + off); off += (size_t)D_HID * D_IN * 2;        // 256 KB
    ushort* w2b  = (ushort*)(ws + off); off += (size_t)D_OUT * D_HID * 2;       // 256 KB
    int* offs     = (int*)(ws + off); off += (size_t)(N + 256) * 4;
    int* cursor   = (int*)(ws + off); off += (size_t)(N + 256) * 4;
    int* bsum     = (int*)(ws + off); off += 1024;
    int2* perm    = (int2*)(ws + off); off += (size_t)E * 8;                    // 6.4 MB

    int nb = (N + SCAN_B - 1) / SCAN_B;
    int n4v = N * (D_IN / 4);
    int bv = (n4v + 255) / 256;
    int bw = 256;                     // 65536 float4s of weights
    int bz = (N + 255) / 256;

    // 1) prep: casts + zero (cursor doubles as cnt)
    prep_kernel<<<bv + bw + bz, 256, 0, stream>>>(v, w1, w2, vb, w1b, w2b,
                                                  cursor, n4v, N, bv, bw);

    // 2) CSR by dst
    hist_kernel<<<(E + 255) / 256, 256, 0, stream>>>(dst, cursor, E);
    scan1_kernel<<<nb, SCAN_B, 0, stream>>>(cursor, offs, bsum, N);
    scan3_kernel<<<nb, SCAN_B, 0, stream>>>(offs, cursor, bsum, N, E, nb);
    fill_kernel<<<(E + 255) / 256, 256, 0, stream>>>(src, dst, ew, cursor, perm, E);

    // 3) aggregate (bf16 gather) -> bf16
    aggregate_kernel<<<(N + 3) / 4, 256, 0, stream>>>(vb, eps, offs, perm, aggb, N);

    // 4) h1b = relu(LN(aggb @ w1b^T + b1))    [fused, 64-row blocks]
    int mblocks = (N + 63) / 64;
    gemm_ln_kernel<D_HID, 1><<<mblocks, 512, 0, stream>>>(
        aggb, w1b, b1, g1, beta1, h1b, N, D_IN);

    // 5) out = relu(LN(h1b @ w2b^T + b2))     [fused, fp32 out]
    gemm_ln_kernel<D_OUT, 0><<<mblocks, 512, 0, stream>>>(
        h1b, w2b, b2, g2, beta2, out, N, D_HID);
}

// Round 9
// 352.099 us; speedup vs baseline: 1.1975x; 1.0048x over previous
//
#include <hip/hip_runtime.h>

#define D_IN 256
#define D_HID 512
#define D_OUT 256
#define LN_EPS 1e-5f
#define SCAN_B 512

typedef __attribute__((ext_vector_type(8))) short bf16x8;
typedef __attribute__((ext_vector_type(4))) float f32x4;

__device__ __forceinline__ ushort f2bf(float x) {
    union { float f; unsigned u; } c; c.f = x;
    unsigned r = c.u + 0x7FFFu + ((c.u >> 16) & 1u);   // round-to-nearest-even
    return (ushort)(r >> 16);
}
__device__ __forceinline__ float bf2f(unsigned b) {
    union { unsigned u; float f; } c; c.u = b << 16;
    return c.f;
}

// ---------------------------------------------------------------------------
// prep: cvt v->bf16 | cvt w1,w2->bf16 | zero cnt     (one launch, grid-split)
// ---------------------------------------------------------------------------
__global__ void prep_kernel(const float* __restrict__ v, const float* __restrict__ w1,
                            const float* __restrict__ w2, ushort* __restrict__ vb,
                            ushort* __restrict__ w1b, ushort* __restrict__ w2b,
                            int* __restrict__ cnt, int n4v, int nzero,
                            int bv, int bw) {
    int b = blockIdx.x, t = threadIdx.x;
    if (b < bv) {
        int i = b * 256 + t;
        if (i < n4v) {
            float4 x = ((const float4*)v)[i];
            ((ushort4*)vb)[i] = make_ushort4(f2bf(x.x), f2bf(x.y), f2bf(x.z), f2bf(x.w));
        }
    } else if (b < bv + bw) {
        int j = (b - bv) * 256 + t;     // 0..65535 float4s (w1: first 32768)
        if (j < 32768) {
            float4 x = ((const float4*)w1)[j];
            ((ushort4*)w1b)[j] = make_ushort4(f2bf(x.x), f2bf(x.y), f2bf(x.z), f2bf(x.w));
        } else {
            int k = j - 32768;
            float4 x = ((const float4*)w2)[k];
            ((ushort4*)w2b)[k] = make_ushort4(f2bf(x.x), f2bf(x.y), f2bf(x.z), f2bf(x.w));
        }
    } else {
        int i = (b - bv - bw) * 256 + t;
        if (i < nzero) cnt[i] = 0;
    }
}

// ---------------------------------------------------------------------------
// CSR build (counting sort by dst)
// ---------------------------------------------------------------------------
__global__ void hist_kernel(const int* __restrict__ dst, int* __restrict__ cnt, int E) {
    int e = blockIdx.x * 256 + threadIdx.x;
    if (e < E) atomicAdd(&cnt[dst[e]], 1);
}

__global__ __launch_bounds__(SCAN_B) void scan1_kernel(const int* __restrict__ cnt,
                                                       int* __restrict__ offs,
                                                       int* __restrict__ bsum, int n) {
    __shared__ int s[SCAN_B];
    int i = blockIdx.x * SCAN_B + threadIdx.x;
    int x = (i < n) ? cnt[i] : 0;
    s[threadIdx.x] = x;
    __syncthreads();
    for (int o = 1; o < SCAN_B; o <<= 1) {
        int t = (threadIdx.x >= (unsigned)o) ? s[threadIdx.x - o] : 0;
        __syncthreads();
        s[threadIdx.x] += t;
        __syncthreads();
    }
    if (i < n) offs[i] = s[threadIdx.x] - x;
    if (threadIdx.x == SCAN_B - 1) bsum[blockIdx.x] = s[threadIdx.x];
}

// offs[i] += sum(bsum[0..blk-1]); cursor=offs; offs[n]=E   (scan2 folded in)
__global__ __launch_bounds__(SCAN_B) void scan3_kernel(int* __restrict__ offs,
                                                       int* __restrict__ cursor,
                                                       const int* __restrict__ bsum,
                                                       int n, int E, int nb) {
    __shared__ int s[SCAN_B];
    int t = threadIdx.x;
    s[t] = (t < nb && t < (int)blockIdx.x) ? bsum[t] : 0;
    __syncthreads();
    for (int o = SCAN_B / 2; o > 0; o >>= 1) {
        if (t < o) s[t] += s[t + o];
        __syncthreads();
    }
    int base = s[0];
    int i = blockIdx.x * SCAN_B + t;
    if (i < n) {
        int v0 = offs[i] + base;
        offs[i] = v0;
        cursor[i] = v0;
    }
    if (i == 0) offs[n] = E;
}

// counting-sort fill: one 8B scatter per edge (src, weight-bits)
__global__ void fill_kernel(const int* __restrict__ src, const int* __restrict__ dst,
                            const float* __restrict__ ew, int* __restrict__ cursor,
                            int2* __restrict__ perm, int E) {
    int e = blockIdx.x * 256 + threadIdx.x;
    if (e >= E) return;
    int p = atomicAdd(&cursor[dst[e]], 1);
    perm[p] = make_int2(src[e], __float_as_int(ew[e]));
}

// ---------------------------------------------------------------------------
// agg_bf16[n] = bf16( eps*vb[n] + sum_{e:dst=n} w_e * vb[src_e] )
// one wave/node, bf16 gather, int2 edge records, unroll x4
// ---------------------------------------------------------------------------
__global__ __launch_bounds__(256) void aggregate_kernel(
    const ushort* __restrict__ vb, const float* __restrict__ eps_p,
    const int* __restrict__ offs, const int2* __restrict__ perm,
    ushort* __restrict__ aggb, int N) {
    int node = blockIdx.x * 4 + (threadIdx.x >> 6);
    if (node >= N) return;
    int lane = threadIdx.x & 63;
    int beg = offs[node], end = offs[node + 1];
    float a0 = 0.f, a1 = 0.f, a2 = 0.f, a3 = 0.f;

    int i = beg;
    for (; i + 4 <= end; i += 4) {
        int2 p0 = perm[i + 0], p1 = perm[i + 1], p2 = perm[i + 2], p3 = perm[i + 3];
        float w0 = __int_as_float(p0.y), w1 = __int_as_float(p1.y);
        float w2 = __int_as_float(p2.y), w3 = __int_as_float(p3.y);
        ushort4 r0 = ((const ushort4*)(vb + (size_t)p0.x * D_IN))[lane];
        ushort4 r1 = ((const ushort4*)(vb + (size_t)p1.x * D_IN))[lane];
        ushort4 r2 = ((const ushort4*)(vb + (size_t)p2.x * D_IN))[lane];
        ushort4 r3 = ((const ushort4*)(vb + (size_t)p3.x * D_IN))[lane];
        a0 += w0 * bf2f(r0.x) + w1 * bf2f(r1.x) + w2 * bf2f(r2.x) + w3 * bf2f(r3.x);
        a1 += w0 * bf2f(r0.y) + w1 * bf2f(r1.y) + w2 * bf2f(r2.y) + w3 * bf2f(r3.y);
        a2 += w0 * bf2f(r0.z) + w1 * bf2f(r1.z) + w2 * bf2f(r2.z) + w3 * bf2f(r3.z);
        a3 += w0 * bf2f(r0.w) + w1 * bf2f(r1.w) + w2 * bf2f(r2.w) + w3 * bf2f(r3.w);
    }
    for (; i < end; ++i) {
        int2 p = perm[i];
        float w = __int_as_float(p.y);
        ushort4 r = ((const ushort4*)(vb + (size_t)p.x * D_IN))[lane];
        a0 += w * bf2f(r.x); a1 += w * bf2f(r.y);
        a2 += w * bf2f(r.z); a3 += w * bf2f(r.w);
    }
    float eps = eps_p[0];
    ushort4 m = ((const ushort4*)(vb + (size_t)node * D_IN))[lane];
    a0 += eps * bf2f(m.x); a1 += eps * bf2f(m.y);
    a2 += eps * bf2f(m.z); a3 += eps * bf2f(m.w);
    ((ushort4*)(aggb + (size_t)node * D_IN))[lane] =
        make_ushort4(f2bf(a0), f2bf(a1), f2bf(a2), f2bf(a3));
}

// ---------------------------------------------------------------------------
// Fused MLP: out[m][:] = relu(LN(relu(LN(agg[m] @ w1^T + b1)) @ w2^T + b2))
// Block = 32 rows, 256 threads / 4 waves. h1 tile lives only in LDS.
// LDS layout (ushort lds[24832] = 49.7 KB):
//   GEMM1: As @0 (32x32=1024), Bs1 @1024 (512x32=16384)
//   h1:    Hs @0, stride 520 (32x520=16640; aliases dead As+Bs1)
//   GEMM2: Bs2 @16640 (256x32=8192)
// Hs stride 520: A-frag reads land 2-way bank-aliased = free (m136).
// ---------------------------------------------------------------------------
#define HSTR 520
#define BS1_OFF 1024
#define BS2_OFF 16640

__global__ __launch_bounds__(256) void mlp_kernel(
    const ushort* __restrict__ A, const ushort* __restrict__ w1b,
    const ushort* __restrict__ w2b,
    const float* __restrict__ b1, const float* __restrict__ g1, const float* __restrict__ be1,
    const float* __restrict__ b2, const float* __restrict__ g2, const float* __restrict__ be2,
    float* __restrict__ out, int N) {
    __shared__ ushort lds[24832];
    __shared__ float red[2][32][4];
    __shared__ float mu_s[32], rs_s[32];

    int t = threadIdx.x;
    int w = t >> 6, lane = t & 63;
    int row0 = blockIdx.x * 32;
    int fr = lane & 15, q = lane >> 4, kb = q * 8;
    int lrow = lane >> 2, lcol = (lane & 3) * 8;

    // ---------------- GEMM1: (32 x 256) @ w1^T -> 32 x 512 ----------------
    f32x4 acc[2][8];
    #pragma unroll
    for (int i = 0; i < 2; ++i)
        #pragma unroll
        for (int c = 0; c < 8; ++c) {
            f32x4 z = {0.f, 0.f, 0.f, 0.f};
            acc[i][c] = z;
        }

    for (int k0 = 0; k0 < D_IN; k0 += 32) {
        if (w < 2) {                       // stage A: 16 rows per wave
            int ar = row0 + w * 16 + lrow;
            if (ar > N - 1) ar = N - 1;
            const ushort* gp = A + (size_t)ar * D_IN + k0 + lcol;
            __builtin_amdgcn_global_load_lds(
                (const __attribute__((address_space(1))) void*)gp,
                (__attribute__((address_space(3))) void*)(&lds[(w * 16) * 32]),
                16, 0, 0);
        }
        #pragma unroll
        for (int c = 0; c < 8; ++c) {      // stage w1 chunk: wave w -> 128 rows
            int br = w * 128 + c * 16 + lrow;
            const ushort* gp = w1b + (size_t)br * D_IN + k0 + lcol;
            __builtin_amdgcn_global_load_lds(
                (const __attribute__((address_space(1))) void*)gp,
                (__attribute__((address_space(3))) void*)(&lds[BS1_OFF + (w * 128 + c * 16) * 32]),
                16, 0, 0);
        }
        __syncthreads();

        bf16x8 af[2], bf[8];
        af[0] = *(const bf16x8*)&lds[fr * 32 + kb];
        af[1] = *(const bf16x8*)&lds[(16 + fr) * 32 + kb];
        #pragma unroll
        for (int c = 0; c < 8; ++c)
            bf[c] = *(const bf16x8*)&lds[BS1_OFF + (w * 128 + c * 16 + fr) * 32 + kb];
        #pragma unroll
        for (int i = 0; i < 2; ++i)
            #pragma unroll
            for (int c = 0; c < 8; ++c)
                acc[i][c] = __builtin_amdgcn_mfma_f32_16x16x32_bf16(af[i], bf[c], acc[i][c], 0, 0, 0);
        __syncthreads();
    }

    // ------------- epilogue 1: bias + LN + ReLU -> Hs (LDS) -------------
    {
        float bi[8], gg[8], bb[8];
        #pragma unroll
        for (int c = 0; c < 8; ++c) {
            int col = w * 128 + c * 16 + fr;
            bi[c] = b1[col]; gg[c] = g1[col]; bb[c] = be1[col];
        }
        #pragma unroll
        for (int i = 0; i < 2; ++i) {
            #pragma unroll
            for (int r = 0; r < 4; ++r) {
                float s = 0.f, sq = 0.f;
                #pragma unroll
                for (int c = 0; c < 8; ++c) {
                    float x = acc[i][c][r] + bi[c];
                    acc[i][c][r] = x;
                    s += x; sq += x * x;
                }
                #pragma unroll
                for (int o = 1; o < 16; o <<= 1) {
                    s  += __shfl_xor(s, o, 64);
                    sq += __shfl_xor(sq, o, 64);
                }
                if (fr == 0) {
                    int row = i * 16 + q * 4 + r;
                    red[0][row][w] = s;
                    red[1][row][w] = sq;
                }
            }
        }
        __syncthreads();
        if (t < 32) {
            float s  = red[0][t][0] + red[0][t][1] + red[0][t][2] + red[0][t][3];
            float sq = red[1][t][0] + red[1][t][1] + red[1][t][2] + red[1][t][3];
            float mu = s / (float)D_HID;
            float var = sq / (float)D_HID - mu * mu;
            mu_s[t] = mu;
            rs_s[t] = rsqrtf(var + LN_EPS);
        }
        __syncthreads();
        #pragma unroll
        for (int i = 0; i < 2; ++i) {
            #pragma unroll
            for (int r = 0; r < 4; ++r) {
                int row = i * 16 + q * 4 + r;
                float mu = mu_s[row], rs = rs_s[row];
                #pragma unroll
                for (int c = 0; c < 8; ++c) {
                    int col = w * 128 + c * 16 + fr;
                    float y = (acc[i][c][r] - mu) * rs * gg[c] + bb[c];
                    lds[row * HSTR + col] = f2bf(fmaxf(y, 0.f));
                }
            }
        }
    }
    // no barrier needed here: GEMM2's first staging barrier orders Hs writes
    // (Bs2 region is disjoint from Hs)

    // ---------------- GEMM2: (32 x 512) @ w2^T -> 32 x 256 ----------------
    f32x4 acc2[2][4];
    #pragma unroll
    for (int i = 0; i < 2; ++i)
        #pragma unroll
        for (int c = 0; c < 4; ++c) {
            f32x4 z = {0.f, 0.f, 0.f, 0.f};
            acc2[i][c] = z;
        }

    for (int k0 = 0; k0 < D_HID; k0 += 32) {
        #pragma unroll
        for (int c = 0; c < 4; ++c) {      // stage w2 chunk: wave w -> 64 rows
            int br = w * 64 + c * 16 + lrow;
            const ushort* gp = w2b + (size_t)br * D_HID + k0 + lcol;
            __builtin_amdgcn_global_load_lds(
                (const __attribute__((address_space(1))) void*)gp,
                (__attribute__((address_space(3))) void*)(&lds[BS2_OFF + (w * 64 + c * 16) * 32]),
                16, 0, 0);
        }
        __syncthreads();

        bf16x8 af[2], bf[4];
        af[0] = *(const bf16x8*)&lds[fr * HSTR + k0 + kb];
        af[1] = *(const bf16x8*)&lds[(16 + fr) * HSTR + k0 + kb];
        #pragma unroll
        for (int c = 0; c < 4; ++c)
            bf[c] = *(const bf16x8*)&lds[BS2_OFF + (w * 64 + c * 16 + fr) * 32 + kb];
        #pragma unroll
        for (int i = 0; i < 2; ++i)
            #pragma unroll
            for (int c = 0; c < 4; ++c)
                acc2[i][c] = __builtin_amdgcn_mfma_f32_16x16x32_bf16(af[i], bf[c], acc2[i][c], 0, 0, 0);
        __syncthreads();
    }

    // ------------- epilogue 2: bias + LN + ReLU -> out (fp32) -------------
    {
        float bi[4], gg[4], bb[4];
        #pragma unroll
        for (int c = 0; c < 4; ++c) {
            int col = w * 64 + c * 16 + fr;
            bi[c] = b2[col]; gg[c] = g2[col]; bb[c] = be2[col];
        }
        #pragma unroll
        for (int i = 0; i < 2; ++i) {
            #pragma unroll
            for (int r = 0; r < 4; ++r) {
                float s = 0.f, sq = 0.f;
                #pragma unroll
                for (int c = 0; c < 4; ++c) {
                    float x = acc2[i][c][r] + bi[c];
                    acc2[i][c][r] = x;
                    s += x; sq += x * x;
                }
                #pragma unroll
                for (int o = 1; o < 16; o <<= 1) {
                    s  += __shfl_xor(s, o, 64);
                    sq += __shfl_xor(sq, o, 64);
                }
                if (fr == 0) {
                    int row = i * 16 + q * 4 + r;
                    red[0][row][w] = s;
                    red[1][row][w] = sq;
                }
            }
        }
        __syncthreads();
        if (t < 32) {
            float s  = red[0][t][0] + red[0][t][1] + red[0][t][2] + red[0][t][3];
            float sq = red[1][t][0] + red[1][t][1] + red[1][t][2] + red[1][t][3];
            float mu = s / (float)D_OUT;
            float var = sq / (float)D_OUT - mu * mu;
            mu_s[t] = mu;
            rs_s[t] = rsqrtf(var + LN_EPS);
        }
        __syncthreads();
        #pragma unroll
        for (int i = 0; i < 2; ++i) {
            #pragma unroll
            for (int r = 0; r < 4; ++r) {
                int row = i * 16 + q * 4 + r;
                int grow = row0 + row;
                if (grow >= N) continue;
                float mu = mu_s[row], rs = rs_s[row];
                #pragma unroll
                for (int c = 0; c < 4; ++c) {
                    int col = w * 64 + c * 16 + fr;
                    float y = (acc2[i][c][r] - mu) * rs * gg[c] + bb[c];
                    out[(size_t)grow * D_OUT + col] = fmaxf(y, 0.f);
                }
            }
        }
    }
}

// ---------------------------------------------------------------------------
extern "C" void kernel_launch(void* const* d_in, const int* in_sizes, int n_in,
                              void* d_out, int out_size, void* d_ws, size_t ws_size,
                              hipStream_t stream) {
    const float* v     = (const float*)d_in[0];
    const float* ew    = (const float*)d_in[1];
    const float* eps   = (const float*)d_in[2];
    const float* w1    = (const float*)d_in[3];
    const float* b1    = (const float*)d_in[4];
    const float* g1    = (const float*)d_in[5];
    const float* beta1 = (const float*)d_in[6];
    const float* w2    = (const float*)d_in[7];
    const float* b2    = (const float*)d_in[8];
    const float* g2    = (const float*)d_in[9];
    const float* beta2 = (const float*)d_in[10];
    const int*   src   = (const int*)d_in[11];
    const int*   dst   = (const int*)d_in[12];

    int N = in_sizes[0] / D_IN;     // 50000
    int E = in_sizes[1];            // 800000

    float* out = (float*)d_out;

    // workspace layout (256B-aligned chunks)
    char* ws = (char*)d_ws;
    size_t off = 0;
    ushort* vb   = (ushort*)(ws + off); off += (size_t)N * D_IN * 2;            // 25.6 MB
    ushort* aggb = (ushort*)(ws + off); off += (size_t)N * D_IN * 2;            // 25.6 MB
    ushort* w1b  = (ushort*)(ws + off); off += (size_t)D_HID * D_IN * 2;        // 256 KB
    ushort* w2b  = (ushort*)(ws + off); off += (size_t)D_OUT * D_HID * 2;       // 256 KB
    int* offs     = (int*)(ws + off); off += (size_t)(N + 256) * 4;
    int* cursor   = (int*)(ws + off); off += (size_t)(N + 256) * 4;
    int* bsum     = (int*)(ws + off); off += 1024;
    int2* perm    = (int2*)(ws + off); off += (size_t)E * 8;                    // 6.4 MB

    int nb = (N + SCAN_B - 1) / SCAN_B;
    int n4v = N * (D_IN / 4);
    int bv = (n4v + 255) / 256;
    int bw = 256;                     // 65536 float4s of weights
    int bz = (N + 255) / 256;

    // 1) prep: casts + zero (cursor doubles as cnt)
    prep_kernel<<<bv + bw + bz, 256, 0, stream>>>(v, w1, w2, vb, w1b, w2b,
                                                  cursor, n4v, N, bv, bw);

    // 2) CSR by dst
    hist_kernel<<<(E + 255) / 256, 256, 0, stream>>>(dst, cursor, E);
    scan1_kernel<<<nb, SCAN_B, 0, stream>>>(cursor, offs, bsum, N);
    scan3_kernel<<<nb, SCAN_B, 0, stream>>>(offs, cursor, bsum, N, E, nb);
    fill_kernel<<<(E + 255) / 256, 256, 0, stream>>>(src, dst, ew, cursor, perm, E);

    // 3) aggregate (bf16 gather) -> bf16
    aggregate_kernel<<<(N + 3) / 4, 256, 0, stream>>>(vb, eps, offs, perm, aggb, N);

    // 4) fused MLP: out = relu(LN(relu(LN(aggb@w1^T+b1))@w2^T+b2))
    int mblocks = (N + 31) / 32;
    mlp_kernel<<<mblocks, 256, 0, stream>>>(aggb, w1b, w2b,
                                            b1, g1, beta1, b2, g2, beta2, out, N);
}